// Round 1
// baseline (142.022 us; speedup 1.0000x reference)
//
#include <hip/hip_runtime.h>
#include <hip/hip_bf16.h>

// Problem constants (from reference): N=100000, F=128, E=640000, OUT=16
#define F_DIM 128
#define OUT_DIM 16

// Kernel 1: P[n][0:16]  = h[n] . W[o][0:128]  + b[o]   (u-projection, bias baked in)
//           P[n][16:32] = h[n] . W[o][128:256]          (v-projection)
// Block = 256 threads = 128 rows x 2 halves. W (16KB) staged in LDS; every wave
// reads W at a wave-uniform address -> LDS broadcast, conflict-free.
__global__ __launch_bounds__(256) void proj_kernel(
    const float* __restrict__ h, const float* __restrict__ W,
    const float* __restrict__ b, float* __restrict__ P, int N)
{
    __shared__ float Ws[16 * 256];   // W copied as-is: row o = [u(128) | v(128)]
    {
        const float4* W4 = (const float4*)W;
        float4* Ws4 = (float4*)Ws;
        #pragma unroll
        for (int i = 0; i < 4; ++i)
            Ws4[threadIdx.x + i * 256] = W4[threadIdx.x + i * 256];
    }
    __syncthreads();

    const int half = threadIdx.x >> 7;              // 0 = u, 1 = v
    const int row  = blockIdx.x * 128 + (threadIdx.x & 127);
    if (row >= N) return;

    const float4* hr = (const float4*)(h + (size_t)row * F_DIM);
    const float* Wbase = Ws + half * 128;

    float acc[16];
    #pragma unroll
    for (int o = 0; o < 16; ++o) acc[o] = 0.0f;

    #pragma unroll 4
    for (int k4 = 0; k4 < 32; ++k4) {
        float4 hv = hr[k4];
        #pragma unroll
        for (int o = 0; o < 16; ++o) {
            const float4 wv = *(const float4*)(Wbase + o * 256 + k4 * 4);
            acc[o] = fmaf(hv.x, wv.x, acc[o]);
            acc[o] = fmaf(hv.y, wv.y, acc[o]);
            acc[o] = fmaf(hv.z, wv.z, acc[o]);
            acc[o] = fmaf(hv.w, wv.w, acc[o]);
        }
    }

    if (half == 0) {
        #pragma unroll
        for (int o = 0; o < 16; ++o) acc[o] += b[o];
    }

    float4* Pq = (float4*)(P + (size_t)row * 32 + half * 16);
    Pq[0] = make_float4(acc[0],  acc[1],  acc[2],  acc[3]);
    Pq[1] = make_float4(acc[4],  acc[5],  acc[6],  acc[7]);
    Pq[2] = make_float4(acc[8],  acc[9],  acc[10], acc[11]);
    Pq[3] = make_float4(acc[12], acc[13], acc[14], acc[15]);
}

// Kernel 2: out[e][o] = P[src[e]][o] + P[dst[e]][16+o].
// 4 lanes per edge, one float4 each -> every wave instruction is 16 contiguous
// 64B chunks (gather) and one fully-coalesced 4KB store.
__global__ __launch_bounds__(256) void gather_kernel(
    const float* __restrict__ P, const int* __restrict__ src,
    const int* __restrict__ dst, float* __restrict__ out, int E)
{
    const int tid = blockIdx.x * blockDim.x + threadIdx.x;
    const int e = tid >> 2;
    const int q = tid & 3;
    if (e >= E) return;
    const int s = src[e];
    const int d = dst[e];
    float4 pu = *(const float4*)(P + (size_t)s * 32 + q * 4);
    float4 pv = *(const float4*)(P + (size_t)d * 32 + 16 + q * 4);
    float4 r;
    r.x = pu.x + pv.x;
    r.y = pu.y + pv.y;
    r.z = pu.z + pv.z;
    r.w = pu.w + pv.w;
    ((float4*)out)[tid] = r;
}

// Fallback (only if workspace is too small to hold P): direct per-(edge,out) dot.
__global__ __launch_bounds__(256) void direct_kernel(
    const float* __restrict__ h, const int* __restrict__ src,
    const int* __restrict__ dst, const float* __restrict__ W,
    const float* __restrict__ b, float* __restrict__ out, int E)
{
    const int tid = blockIdx.x * blockDim.x + threadIdx.x;
    if (tid >= E * OUT_DIM) return;
    const int e = tid >> 4;
    const int o = tid & 15;
    const float* hu = h + (size_t)src[e] * F_DIM;
    const float* hv = h + (size_t)dst[e] * F_DIM;
    const float* wu = W + (size_t)o * 256;
    const float* wv = wu + 128;
    float acc = b[o];
    for (int k = 0; k < 128; ++k) acc = fmaf(hu[k], wu[k], acc);
    for (int k = 0; k < 128; ++k) acc = fmaf(hv[k], wv[k], acc);
    out[tid] = acc;
}

extern "C" void kernel_launch(void* const* d_in, const int* in_sizes, int n_in,
                              void* d_out, int out_size, void* d_ws, size_t ws_size,
                              hipStream_t stream) {
    const float* h   = (const float*)d_in[0];
    const int*   src = (const int*)d_in[1];
    const int*   dst = (const int*)d_in[2];
    const float* W   = (const float*)d_in[3];
    const float* b   = (const float*)d_in[4];
    float* out = (float*)d_out;

    const int N = in_sizes[0] / F_DIM;     // 100000
    const int E = in_sizes[1];             // 640000

    const size_t p_bytes = (size_t)N * 32 * sizeof(float);  // 12.8 MB

    if (ws_size >= p_bytes) {
        float* P = (float*)d_ws;
        const int blocks1 = (N + 127) / 128;
        proj_kernel<<<blocks1, 256, 0, stream>>>(h, W, b, P, N);
        const int total2 = E * 4;
        const int blocks2 = (total2 + 255) / 256;
        gather_kernel<<<blocks2, 256, 0, stream>>>(P, src, dst, out, E);
    } else {
        const int total = E * OUT_DIM;
        const int blocks = (total + 255) / 256;
        direct_kernel<<<blocks, 256, 0, stream>>>(h, src, dst, W, b, out, E);
    }
}

// Round 2
// 138.593 us; speedup vs baseline: 1.0247x; 1.0247x over previous
//
#include <hip/hip_runtime.h>
#include <hip/hip_bf16.h>

// Problem constants (from reference): N=100000, F=128, E=640000, OUT=16
#define F_DIM 128
#define OUT_DIM 16

// ---------------------------------------------------------------------------
// Kernel 0: transpose W[16][256] -> Wt[128][32]:
//   Wt[k*32 + o]      = W[o*256 + k]        (u weights)
//   Wt[k*32 + 16 + o] = W[o*256 + 128 + k]  (v weights)
// Makes the proj inner-loop W access contiguous + wave-uniform -> s_load.
__global__ __launch_bounds__(256) void wtrans_kernel(
    const float* __restrict__ W, float* __restrict__ Wt)
{
    int tid = blockIdx.x * 256 + threadIdx.x;   // 0..4095
    if (tid >= 128 * 32) return;
    int k   = tid >> 5;
    int j   = tid & 31;
    int o   = j & 15;
    int sel = j >> 4;
    Wt[tid] = W[o * 256 + sel * 128 + k];
}

// ---------------------------------------------------------------------------
// Kernel 1: P[n][0:16] = h[n].Wu + b ; P[n][16:32] = h[n].Wv
// Block 256 = 4 waves; 128 rows/block. half = t>>7 (wave-uniform).
// h staged in LDS via coalesced loads, XOR-swizzled (c = k4 ^ (r&7)) so both
// the staging ds_write_b128 and compute ds_read_b128 are phase-minimal.
// W read via wave-uniform index -> scalar loads (s_load_dwordx16), so the
// inner loop is pure v_fmac_f32 with one SGPR source. VALU floor ~5.2us,
// HBM floor (51MB h) ~8us.
__global__ __launch_bounds__(256) void proj_kernel(
    const float* __restrict__ h, const float* __restrict__ Wt,
    const float* __restrict__ b, float* __restrict__ P, int N)
{
    __shared__ float hs[128 * 64];   // 32 KB per 64-k chunk

    const int t    = threadIdx.x;
    const int half = __builtin_amdgcn_readfirstlane(t >> 7);  // 0=u, 1=v
    const int r    = t & 127;                                  // LDS row
    const int row0 = blockIdx.x * 128;

    float acc[16];
    #pragma unroll
    for (int o = 0; o < 16; ++o) acc[o] = 0.0f;

    for (int ck = 0; ck < 2; ++ck) {
        const int kbase = ck * 64;
        // ---- stage 128 rows x 64 k into LDS (coalesced: 16 lanes cover one
        //      row's 256B; swizzled write is conflict-free) ----
        #pragma unroll
        for (int i = 0; i < 8; ++i) {
            int f  = i * 256 + t;
            int sr = f >> 4;          // 0..127 row in tile
            int k4 = f & 15;          // float4 group within chunk
            int g  = row0 + sr;
            if (g >= N) g = N - 1;    // clamp (redundant loads, correct)
            const float4 v = *(const float4*)(h + (size_t)g * F_DIM + kbase + k4 * 4);
            int c = k4 ^ (sr & 7);
            *(float4*)(hs + sr * 64 + c * 4) = v;
        }
        __syncthreads();

        // ---- compute: per k-group, 1 conflict-free ds_read_b128 + 64 FMA
        //      with W from SGPRs ----
        #pragma unroll 4
        for (int K4 = 0; K4 < 16; ++K4) {
            int c = K4 ^ (r & 7);
            const float4 hv = *(const float4*)(hs + r * 64 + c * 4);
            const float* wrow = Wt + (size_t)(kbase + K4 * 4) * 32 + half * 16;
            #pragma unroll
            for (int j = 0; j < 4; ++j) {
                const float hk = (&hv.x)[j];
                #pragma unroll
                for (int o = 0; o < 16; ++o)
                    acc[o] = fmaf(wrow[j * 32 + o], hk, acc[o]);
            }
        }
        __syncthreads();
    }

    const int grow = row0 + r;
    if (grow < N) {
        if (half == 0) {
            #pragma unroll
            for (int o = 0; o < 16; ++o) acc[o] += b[o];  // uniform s_load
        }
        float4* Pq = (float4*)(P + (size_t)grow * 32 + half * 16);
        Pq[0] = make_float4(acc[0],  acc[1],  acc[2],  acc[3]);
        Pq[1] = make_float4(acc[4],  acc[5],  acc[6],  acc[7]);
        Pq[2] = make_float4(acc[8],  acc[9],  acc[10], acc[11]);
        Pq[3] = make_float4(acc[12], acc[13], acc[14], acc[15]);
    }
}

// ---------------------------------------------------------------------------
// Kernel 2: out[e][o] = P[src[e]][o] + P[dst[e]][16+o].
// 4 lanes/edge, one float4 each; stores fully coalesced; gathers are 64B
// segments served mostly from L2/L3 (P = 12.8 MB).
__global__ __launch_bounds__(256) void gather_kernel(
    const float* __restrict__ P, const int* __restrict__ src,
    const int* __restrict__ dst, float* __restrict__ out, int E)
{
    const int tid = blockIdx.x * blockDim.x + threadIdx.x;
    const int e = tid >> 2;
    const int q = tid & 3;
    if (e >= E) return;
    const int s = src[e];
    const int d = dst[e];
    float4 pu = *(const float4*)(P + (size_t)s * 32 + q * 4);
    float4 pv = *(const float4*)(P + (size_t)d * 32 + 16 + q * 4);
    float4 r;
    r.x = pu.x + pv.x;
    r.y = pu.y + pv.y;
    r.z = pu.z + pv.z;
    r.w = pu.w + pv.w;
    ((float4*)out)[tid] = r;
}

// Fallback (only if workspace is too small to hold P+Wt): direct per-(e,o) dot.
__global__ __launch_bounds__(256) void direct_kernel(
    const float* __restrict__ h, const int* __restrict__ src,
    const int* __restrict__ dst, const float* __restrict__ W,
    const float* __restrict__ b, float* __restrict__ out, int E)
{
    const int tid = blockIdx.x * blockDim.x + threadIdx.x;
    if (tid >= E * OUT_DIM) return;
    const int e = tid >> 4;
    const int o = tid & 15;
    const float* hu = h + (size_t)src[e] * F_DIM;
    const float* hv = h + (size_t)dst[e] * F_DIM;
    const float* wu = W + (size_t)o * 256;
    const float* wv = wu + 128;
    float acc = b[o];
    for (int k = 0; k < 128; ++k) acc = fmaf(hu[k], wu[k], acc);
    for (int k = 0; k < 128; ++k) acc = fmaf(hv[k], wv[k], acc);
    out[tid] = acc;
}

extern "C" void kernel_launch(void* const* d_in, const int* in_sizes, int n_in,
                              void* d_out, int out_size, void* d_ws, size_t ws_size,
                              hipStream_t stream) {
    const float* h   = (const float*)d_in[0];
    const int*   src = (const int*)d_in[1];
    const int*   dst = (const int*)d_in[2];
    const float* W   = (const float*)d_in[3];
    const float* b   = (const float*)d_in[4];
    float* out = (float*)d_out;

    const int N = in_sizes[0] / F_DIM;     // 100000
    const int E = in_sizes[1];             // 640000

    const size_t p_bytes  = (size_t)N * 32 * sizeof(float);        // 12.8 MB
    const size_t p_al     = (p_bytes + 255) & ~(size_t)255;
    const size_t wt_bytes = 128 * 32 * sizeof(float);              // 16 KB

    if (ws_size >= p_al + wt_bytes) {
        float* P  = (float*)d_ws;
        float* Wt = (float*)((char*)d_ws + p_al);

        wtrans_kernel<<<16, 256, 0, stream>>>(W, Wt);

        const int blocks1 = (N + 127) / 128;
        proj_kernel<<<blocks1, 256, 0, stream>>>(h, Wt, b, P, N);

        const int total2  = E * 4;
        const int blocks2 = (total2 + 255) / 256;
        gather_kernel<<<blocks2, 256, 0, stream>>>(P, src, dst, out, E);
    } else {
        const int total  = E * OUT_DIM;
        const int blocks = (total + 255) / 256;
        direct_kernel<<<blocks, 256, 0, stream>>>(h, src, dst, W, b, out, E);
    }
}

// Round 4
// 131.658 us; speedup vs baseline: 1.0787x; 1.0527x over previous
//
#include <hip/hip_runtime.h>
#include <hip/hip_bf16.h>

// Problem constants (from reference): N=100000, F=128, E=640000, OUT=16
#define F_DIM 128
#define OUT_DIM 16

typedef _Float16 half8 __attribute__((ext_vector_type(8)));
typedef float floatx4 __attribute__((ext_vector_type(4)));

// ---------------------------------------------------------------------------
// Kernel 0: build fp16 hi/lo B-fragments for mfma_f32_16x16x32_f16.
// B[k][n] fragment layout: lane holds n = lane&15, k = (lane>>4)*8 + j.
// n is the output index within half t (t=0: u-weights W[o][k], t=1: v-weights
// W[o][128+k]). Table = 4 k-steps x 2 halves x 64 lanes x 8 = 4096 elems per
// term (8 KB); L1/L2-resident for the proj kernel.
__global__ __launch_bounds__(256) void wprep_kernel(
    const float* __restrict__ W, _Float16* __restrict__ Bhi,
    _Float16* __restrict__ Blo)
{
    int tid = blockIdx.x * 256 + threadIdx.x;     // 0..4095
    if (tid >= 4096) return;
    int j    = tid & 7;
    int lane = (tid >> 3) & 63;
    int t    = (tid >> 9) & 1;
    int s    = (tid >> 10) & 3;
    int n = lane & 15;
    int q = lane >> 4;
    int k = s * 32 + q * 8 + j;
    float w = W[n * 256 + t * 128 + k];
    _Float16 hi = (_Float16)w;
    _Float16 lo = (_Float16)(w - (float)hi);
    Bhi[tid] = hi;
    Blo[tid] = lo;
}

// ---------------------------------------------------------------------------
// Kernel 1: P[n][0:16] = h[n].Wu + b ; P[n][16:32] = h[n].Wv  via fp16 MFMA
// hi/lo split: D += Ahi*Bhi + Ahi*Blo + Alo*Bhi  (error ~2^-22 relative).
// Each wave computes a 16-row x 32-col tile; A-frags load DIRECTLY from
// global h (lane=(q,m): h[row0+m][s*32+q*8+j], wave covers 16 rows x 128B
// contiguous spans -> line-complete, full DRAM efficiency). No LDS.
// Layouts (HW-verified per guide): A[m=lane&15][k=quad*8+j],
// B[k][n=lane&15], C/D row=quad*4+reg, col=lane&15.
__global__ __launch_bounds__(256) void proj_mfma_kernel(
    const float* __restrict__ h, const _Float16* __restrict__ Bhi,
    const _Float16* __restrict__ Blo, const float* __restrict__ b,
    float* __restrict__ P, int N)
{
    const int lane = threadIdx.x & 63;
    const int wave = threadIdx.x >> 6;
    const int n = lane & 15;
    const int q = lane >> 4;
    const int row_base = blockIdx.x * 64 + wave * 16;
    if (row_base >= N) return;          // no __syncthreads below: safe

    int arow = row_base + n;            // A-operand row this lane feeds
    if (arow >= N) arow = N - 1;        // clamped rows only affect unstored D rows
    const float* hrow = h + (size_t)arow * F_DIM + q * 8;

    floatx4 c0 = {0.f, 0.f, 0.f, 0.f};
    floatx4 c1 = {0.f, 0.f, 0.f, 0.f};

    #pragma unroll
    for (int s = 0; s < 4; ++s) {
        // ---- A: 8 consecutive fp32 of this lane's row, split hi/lo ----
        float av[8];
        *(float4*)(av)     = *(const float4*)(hrow + s * 32);
        *(float4*)(av + 4) = *(const float4*)(hrow + s * 32 + 4);
        half8 ah, al;
        #pragma unroll
        for (int j = 0; j < 8; ++j) {
            _Float16 hi = (_Float16)av[j];
            ah[j] = hi;
            al[j] = (_Float16)(av[j] - (float)hi);
        }
        // ---- B frags for this k-step (uniform across waves, L1-hot) ----
        const int base0 = (s * 2 + 0) * 512 + lane * 8;
        const int base1 = (s * 2 + 1) * 512 + lane * 8;
        half8 bh0 = *(const half8*)(Bhi + base0);
        half8 bl0 = *(const half8*)(Blo + base0);
        half8 bh1 = *(const half8*)(Bhi + base1);
        half8 bl1 = *(const half8*)(Blo + base1);

        c0 = __builtin_amdgcn_mfma_f32_16x16x32_f16(ah, bh0, c0, 0, 0, 0);
        c0 = __builtin_amdgcn_mfma_f32_16x16x32_f16(ah, bl0, c0, 0, 0, 0);
        c0 = __builtin_amdgcn_mfma_f32_16x16x32_f16(al, bh0, c0, 0, 0, 0);
        c1 = __builtin_amdgcn_mfma_f32_16x16x32_f16(ah, bh1, c1, 0, 0, 0);
        c1 = __builtin_amdgcn_mfma_f32_16x16x32_f16(ah, bl1, c1, 0, 0, 0);
        c1 = __builtin_amdgcn_mfma_f32_16x16x32_f16(al, bh1, c1, 0, 0, 0);
    }

    const float bn = b[n];
    #pragma unroll
    for (int reg = 0; reg < 4; ++reg) {
        int row = row_base + q * 4 + reg;
        if (row < N) {
            P[(size_t)row * 32 + n]      = c0[reg] + bn;  // u half + bias
            P[(size_t)row * 32 + 16 + n] = c1[reg];       // v half
        }
    }
}

// ---------------------------------------------------------------------------
// Kernel 2: out[e][o] = P[src[e]][o] + P[dst[e]][16+o].
// 4 lanes/edge, one float4 each; stores fully coalesced + nontemporal (keep
// L2 for the 12.8MB P gather table). Gathers are 64B segments from L2/L3.
// NOTE: nontemporal builtin needs a clang ext_vector pointer, not HIP float4.
__global__ __launch_bounds__(256) void gather_kernel(
    const float* __restrict__ P, const int* __restrict__ src,
    const int* __restrict__ dst, float* __restrict__ out, int E)
{
    const int tid = blockIdx.x * blockDim.x + threadIdx.x;
    const int e = tid >> 2;
    const int q = tid & 3;
    if (e >= E) return;
    const int s = src[e];
    const int d = dst[e];
    const floatx4 pu = *(const floatx4*)(P + (size_t)s * 32 + q * 4);
    const floatx4 pv = *(const floatx4*)(P + (size_t)d * 32 + 16 + q * 4);
    const floatx4 r = pu + pv;
    __builtin_nontemporal_store(r, (floatx4*)out + tid);
}

// Fallback (only if workspace too small): direct per-(edge,out) dot, fp32.
__global__ __launch_bounds__(256) void direct_kernel(
    const float* __restrict__ h, const int* __restrict__ src,
    const int* __restrict__ dst, const float* __restrict__ W,
    const float* __restrict__ b, float* __restrict__ out, int E)
{
    const int tid = blockIdx.x * blockDim.x + threadIdx.x;
    if (tid >= E * OUT_DIM) return;
    const int e = tid >> 4;
    const int o = tid & 15;
    const float* hu = h + (size_t)src[e] * F_DIM;
    const float* hv = h + (size_t)dst[e] * F_DIM;
    const float* wu = W + (size_t)o * 256;
    const float* wv = wu + 128;
    float acc = b[o];
    for (int k = 0; k < 128; ++k) acc = fmaf(hu[k], wu[k], acc);
    for (int k = 0; k < 128; ++k) acc = fmaf(hv[k], wv[k], acc);
    out[tid] = acc;
}

extern "C" void kernel_launch(void* const* d_in, const int* in_sizes, int n_in,
                              void* d_out, int out_size, void* d_ws, size_t ws_size,
                              hipStream_t stream) {
    const float* h   = (const float*)d_in[0];
    const int*   src = (const int*)d_in[1];
    const int*   dst = (const int*)d_in[2];
    const float* W   = (const float*)d_in[3];
    const float* b   = (const float*)d_in[4];
    float* out = (float*)d_out;

    const int N = in_sizes[0] / F_DIM;     // 100000
    const int E = in_sizes[1];             // 640000

    const size_t p_bytes  = (size_t)N * 32 * sizeof(float);        // 12.8 MB
    const size_t p_al     = (p_bytes + 255) & ~(size_t)255;
    const size_t bf_bytes = 4096 * sizeof(_Float16);               // 8 KB each

    if (ws_size >= p_al + 2 * bf_bytes) {
        float*    P   = (float*)d_ws;
        _Float16* Bhi = (_Float16*)((char*)d_ws + p_al);
        _Float16* Blo = Bhi + 4096;

        wprep_kernel<<<16, 256, 0, stream>>>(W, Bhi, Blo);

        const int blocks1 = (N + 63) / 64;
        proj_mfma_kernel<<<blocks1, 256, 0, stream>>>(h, Bhi, Blo, b, P, N);

        const int total2  = E * 4;
        const int blocks2 = (total2 + 255) / 256;
        gather_kernel<<<blocks2, 256, 0, stream>>>(P, src, dst, out, E);
    } else {
        const int total  = E * OUT_DIM;
        const int blocks = (total + 255) / 256;
        direct_kernel<<<blocks, 256, 0, stream>>>(h, src, dst, W, b, out, E);
    }
}